// Round 7
// baseline (216.100 us; speedup 1.0000x reference)
//
#include <hip/hip_runtime.h>
#include <hip/hip_bf16.h>
#include <math.h>

#define NNODES 131072
#define BN 32
#define TILES 4

typedef __attribute__((ext_vector_type(8))) short bf16x8;
typedef __attribute__((ext_vector_type(4))) float f32x4;

// bf16 weights (prep): W_h [128*64] @0 | W_s [128*256] @8192 | W_g [64*128] @40960
__device__ short g_w[49152];
// bf16 fused weight Wc[o][v] = sum_h W_V[o][h]*W_h[h][v], [64*64] row-major
__device__ short g_wc[4096];

__device__ __forceinline__ short f2b(float f) {
  union { float f; unsigned u; } x; x.f = f;
  unsigned r = x.u + 0x7fffu + ((x.u >> 16) & 1u);
  return (short)(r >> 16);
}

__global__ void prep_kernel(const float* __restrict__ W_h, const float* __restrict__ W_V,
                            const float* __restrict__ W_s_w, const float* __restrict__ W_g_w) {
  int b = blockIdx.x;
  if (b < 48) {
    int i4 = (b * 256 + threadIdx.x) * 4;
    const float* src;
    if (i4 < 8192)       src = W_h   + i4;
    else if (i4 < 40960) src = W_s_w + (i4 - 8192);
    else                 src = W_g_w + (i4 - 40960);
    float4 q = *(const float4*)src;
    short4 p;
    p.x = f2b(q.x); p.y = f2b(q.y); p.z = f2b(q.z); p.w = f2b(q.w);
    *(short4*)(g_w + i4) = p;
  } else {
    // Wc = W_V @ W_h : 4096 entries, 4 blocks x 256 threads x 4 entries
    int gid = (b - 48) * 256 + threadIdx.x;   // 0..1023
    int o  = gid >> 4;
    int v0 = (gid & 15) * 4;
    float a0 = 0.f, a1 = 0.f, a2 = 0.f, a3 = 0.f;
    #pragma unroll 8
    for (int h = 0; h < 128; ++h) {
      float wv = W_V[o * 128 + h];
      float4 wh = *(const float4*)(W_h + h * 64 + v0);
      a0 += wv * wh.x; a1 += wv * wh.y; a2 += wv * wh.z; a3 += wv * wh.w;
    }
    short4 p;
    p.x = f2b(a0); p.y = f2b(a1); p.z = f2b(a2); p.w = f2b(a3);
    *(short4*)(g_wc + o * 64 + v0) = p;
  }
}

// LDS (36864 B -> 4 blocks/CU):
//   Vt   @0     (12288): [96][64]  bf16 s128 swz   rows c*32+nl
//   SC   @12288 (8192) : [32][128] bf16 s256 swz   staged s
//   NORM @20480 (8192) : [32][128] bf16 s256 swz
//   SOUT @28672 (8192) : [32][128] bf16 s256 swz
//   VST  @0     (24576): [32][192] f32  overlays Vt+SC+NORM-head
// Per tile: B1 (Vt/SC ready), B2 (NORM ready; GEMM3 s-half already done),
//           B3 (SOUT ready), B4 (VST ready), B5 (VST reads done; only if more tiles).
// Next tile's V/s prefetched into registers right after LDS stage writes.

__global__ __launch_bounds__(256, 4)
void gvp_kernel(const float* __restrict__ s_in, const float* __restrict__ V_in,
                const float* __restrict__ W_s_b, const float* __restrict__ W_g_b,
                float* __restrict__ s_out_g, float* __restrict__ V_out_g)
{
  __shared__ __align__(16) char smem[36864];
  char*  const Vt   = smem;
  float* const VST  = (float*)smem;
  char*  const SC   = smem + 12288;
  char*  const NORM = smem + 20480;
  char*  const SOUT = smem + 28672;

  const short* const g_wh = g_w;
  const short* const g_ws = g_w + 8192;
  const short* const g_wg = g_w + 40960;

  const int t    = threadIdx.x;
  const int lane = t & 63;
  const int w    = t >> 6;
  const int l15  = lane & 15;
  const int lk8  = (lane >> 4) << 3;  // 0,8,16,24 : k-offset of A/B frag
  const int r4   = (lane >> 4) << 2;  // 0,4,8,12  : row-offset of C frag
  const long base = (long)blockIdx.x * (BN * TILES);

  // ---- loop-invariant weight fragments + biases ----
  bf16x8 bf1[2][2];
  #pragma unroll
  for (int cc = 0; cc < 2; ++cc) {
    int h = ((2 * w + cc) << 4) + l15;
    #pragma unroll
    for (int ks = 0; ks < 2; ++ks)
      bf1[cc][ks] = *(const bf16x8*)(g_wh + h * 64 + (ks << 5) + lk8);
  }
  bf16x8 bc[2];
  {
    int o = (w << 4) + l15;
    bc[0] = *(const bf16x8*)(g_wc + o * 64 + lk8);
    bc[1] = *(const bf16x8*)(g_wc + o * 64 + 32 + lk8);
  }
  const float bias0 = W_s_b[(w << 5) + l15];
  const float bias1 = W_s_b[(w << 5) + 16 + l15];
  const float biasg = W_g_b[(w << 4) + l15];

  // ---- preload tile 0 into registers ----
  float4 vr[6], sr[4];
  {
    const float4* Vb = (const float4*)(V_in + base * 192);
    const float4* sb = (const float4*)(s_in + base * 128);
    #pragma unroll
    for (int i = 0; i < 6; ++i) vr[i] = Vb[t + 256 * i];
    #pragma unroll
    for (int i = 0; i < 4; ++i) sr[i] = sb[t + 256 * i];
  }

  for (int tt = 0; tt < TILES; ++tt) {
    const long n0 = base + (long)tt * BN;

    // ---- LDS stage: Vt from vr ----
    #pragma unroll
    for (int i = 0; i < 6; ++i) {
      int f = (t + 256 * i) << 2;
      float4 q = vr[i];
      #pragma unroll
      for (int e = 0; e < 4; ++e) {
        int ff = f + e;
        int nl = ff / 192;
        int r  = ff - nl * 192;
        int v  = r / 3;
        int c  = r - v * 3;
        int row = (c << 5) + nl;
        unsigned a = (unsigned)(row * 128) + (((unsigned)(v * 2)) ^ (unsigned)((row & 7) << 4));
        *(short*)(Vt + a) = f2b(((const float*)&q)[e]);
      }
    }
    // ---- LDS stage: SC from sr ----
    #pragma unroll
    for (int i = 0; i < 4; ++i) {
      int f = (t + 256 * i) << 2;
      float4 q = sr[i];
      int nl = f >> 7;
      int k  = f & 127;
      ushort4 p;
      p.x = (unsigned short)f2b(q.x);
      p.y = (unsigned short)f2b(q.y);
      p.z = (unsigned short)f2b(q.z);
      p.w = (unsigned short)f2b(q.w);
      unsigned a = (unsigned)(nl * 256) + (((unsigned)(k * 2)) ^ (unsigned)((nl & 7) << 4));
      *(ushort4*)(SC + a) = p;
    }

    // ---- issue next-tile prefetch (latency hides under GEMM1..GEMM3) ----
    if (tt + 1 < TILES) {
      const float4* Vb = (const float4*)(V_in + (n0 + BN) * 192);
      const float4* sb = (const float4*)(s_in + (n0 + BN) * 128);
      #pragma unroll
      for (int i = 0; i < 6; ++i) vr[i] = Vb[t + 256 * i];
      #pragma unroll
      for (int i = 0; i < 4; ++i) sr[i] = sb[t + 256 * i];
    }
    __syncthreads();  // B1: Vt/SC visible

    // ---- GEMM1 (Vh) + GEMM2 (V_out_pre via fused Wc), shared Vt A-frags, K=64 ----
    f32x4 acc1[6][2];
    f32x4 acc2[6];
    #pragma unroll
    for (int rt = 0; rt < 6; ++rt) {
      f32x4 z = {0.f, 0.f, 0.f, 0.f};
      acc1[rt][0] = z; acc1[rt][1] = z; acc2[rt] = z;
    }
    #pragma unroll
    for (int rt = 0; rt < 6; ++rt) {
      int row = (rt << 4) + l15;
      unsigned sw = (unsigned)((row & 7) << 4);
      bf16x8 af0 = *(const bf16x8*)(Vt + row * 128 + (((unsigned)(lk8 * 2)) ^ sw));
      bf16x8 af1 = *(const bf16x8*)(Vt + row * 128 + (((unsigned)((32 + lk8) * 2)) ^ sw));
      #pragma unroll
      for (int cc = 0; cc < 2; ++cc) {
        acc1[rt][cc] = __builtin_amdgcn_mfma_f32_16x16x32_bf16(af0, bf1[cc][0], acc1[rt][cc], 0, 0, 0);
        acc1[rt][cc] = __builtin_amdgcn_mfma_f32_16x16x32_bf16(af1, bf1[cc][1], acc1[rt][cc], 0, 0, 0);
      }
      acc2[rt] = __builtin_amdgcn_mfma_f32_16x16x32_bf16(af0, bc[0], acc2[rt], 0, 0, 0);
      acc2[rt] = __builtin_amdgcn_mfma_f32_16x16x32_bf16(af1, bc[1], acc2[rt], 0, 0, 0);
    }

    // ---- Vh_norm -> NORM ----
    #pragma unroll
    for (int cc = 0; cc < 2; ++cc) {
      int col = ((2 * w + cc) << 4) + l15;
      #pragma unroll
      for (int rt = 0; rt < 2; ++rt) {
        #pragma unroll
        for (int i = 0; i < 4; ++i) {
          int nl = (rt << 4) + r4 + i;
          float x0 = acc1[rt][cc][i];
          float x1 = acc1[rt + 2][cc][i];
          float x2 = acc1[rt + 4][cc][i];
          float nrm = sqrtf(x0 * x0 + x1 * x1 + x2 * x2);
          unsigned a = (unsigned)(nl * 256) + (((unsigned)(col * 2)) ^ (unsigned)((nl & 7) << 4));
          *(short*)(NORM + a) = f2b(nrm);
        }
      }
    }

    // ---- GEMM3 s-half (ks 0..3 from SC) BEFORE the NORM barrier ----
    f32x4 acc3[2][2];
    {
      f32x4 z = {0.f, 0.f, 0.f, 0.f};
      acc3[0][0] = z; acc3[0][1] = z; acc3[1][0] = z; acc3[1][1] = z;
    }
    #pragma unroll
    for (int ks = 0; ks < 4; ++ks) {
      bf16x8 b3[2];
      #pragma unroll
      for (int cc = 0; cc < 2; ++cc) {
        int o = (w << 5) + (cc << 4) + l15;
        b3[cc] = *(const bf16x8*)(g_ws + o * 256 + (ks << 5) + lk8);
      }
      #pragma unroll
      for (int rt = 0; rt < 2; ++rt) {
        int row = (rt << 4) + l15;
        unsigned sw = (unsigned)((row & 7) << 4);
        bf16x8 a = *(const bf16x8*)(SC + row * 256 + (((unsigned)(((ks << 5) + lk8) * 2)) ^ sw));
        acc3[rt][0] = __builtin_amdgcn_mfma_f32_16x16x32_bf16(a, b3[0], acc3[rt][0], 0, 0, 0);
        acc3[rt][1] = __builtin_amdgcn_mfma_f32_16x16x32_bf16(a, b3[1], acc3[rt][1], 0, 0, 0);
      }
    }
    __syncthreads();  // B2: NORM visible

    // ---- GEMM3 norm-half (ks 4..7 from NORM) ----
    #pragma unroll
    for (int ks = 4; ks < 8; ++ks) {
      bf16x8 b3[2];
      #pragma unroll
      for (int cc = 0; cc < 2; ++cc) {
        int o = (w << 5) + (cc << 4) + l15;
        b3[cc] = *(const bf16x8*)(g_ws + o * 256 + (ks << 5) + lk8);
      }
      #pragma unroll
      for (int rt = 0; rt < 2; ++rt) {
        int row = (rt << 4) + l15;
        unsigned sw = (unsigned)((row & 7) << 4);
        bf16x8 a = *(const bf16x8*)(NORM + row * 256 + (((unsigned)((((ks - 4) << 5) + lk8) * 2)) ^ sw));
        acc3[rt][0] = __builtin_amdgcn_mfma_f32_16x16x32_bf16(a, b3[0], acc3[rt][0], 0, 0, 0);
        acc3[rt][1] = __builtin_amdgcn_mfma_f32_16x16x32_bf16(a, b3[1], acc3[rt][1], 0, 0, 0);
      }
    }

    // ---- s_out epilogue: line-local global stores + SOUT stage ----
    #pragma unroll
    for (int rt = 0; rt < 2; ++rt) {
      #pragma unroll
      for (int i = 0; i < 4; ++i) {
        int row = (rt << 4) + r4 + i;
        unsigned sw = (unsigned)((row & 7) << 4);
        float v0 = fmaxf(acc3[rt][0][i] + bias0, 0.0f);
        float v1 = fmaxf(acc3[rt][1][i] + bias1, 0.0f);
        int col0 = (w << 5) + l15;
        s_out_g[(n0 + row) * 128 + col0]      = v0;
        s_out_g[(n0 + row) * 128 + col0 + 16] = v1;
        unsigned a0 = (unsigned)(row * 256) + (((unsigned)(col0 * 2)) ^ sw);
        unsigned a1 = (unsigned)(row * 256) + (((unsigned)((col0 + 16) * 2)) ^ sw);
        *(short*)(SOUT + a0) = f2b(v0);
        *(short*)(SOUT + a1) = f2b(v1);
      }
    }
    __syncthreads();  // B3: SOUT ready

    // ---- GEMM4: gate = sigmoid(s_out·W_g^T + b); C-frag lane-aligned with acc2 ----
    f32x4 acc4[2];
    { f32x4 z = {0.f, 0.f, 0.f, 0.f}; acc4[0] = z; acc4[1] = z; }
    {
      int o = (w << 4) + l15;
      #pragma unroll
      for (int ks = 0; ks < 4; ++ks) {
        bf16x8 b4 = *(const bf16x8*)(g_wg + o * 128 + (ks << 5) + lk8);
        #pragma unroll
        for (int rt = 0; rt < 2; ++rt) {
          int row = (rt << 4) + l15;
          bf16x8 a = *(const bf16x8*)(SOUT + row * 256 +
                       (((unsigned)(((ks << 5) + lk8) * 2)) ^ ((unsigned)((row & 7) << 4))));
          acc4[rt] = __builtin_amdgcn_mfma_f32_16x16x32_bf16(a, b4, acc4[rt], 0, 0, 0);
        }
      }
    }

    // ---- gate apply (in-lane) -> VST [32][192] f32 (overlays Vt+SC+NORM-head) ----
    {
      int col = (w << 4) + l15;
      #pragma unroll
      for (int rt = 0; rt < 6; ++rt) {
        #pragma unroll
        for (int i = 0; i < 4; ++i) {
          int c   = rt >> 1;
          int nlg = rt & 1;
          int nl  = (nlg << 4) + r4 + i;
          float x = acc4[nlg][i] + biasg;
          float sg = 1.0f / (1.0f + __expf(-x));
          VST[nl * 192 + col * 3 + c] = acc2[rt][i] * sg;
        }
      }
    }
    __syncthreads();  // B4: VST visible

    // ---- coalesced full-line V_out store (float4 x 64 lanes = 1KB/instr) ----
    {
      float4* Vo = (float4*)(V_out_g + n0 * 192);
      const float4* Vs = (const float4*)VST;
      #pragma unroll
      for (int i = 0; i < 6; ++i) {
        int idx = t + 256 * i;
        Vo[idx] = Vs[idx];
      }
    }
    if (tt + 1 < TILES) __syncthreads();  // B5: VST reads done before next stage
  }
}

extern "C" void kernel_launch(void* const* d_in, const int* in_sizes, int n_in,
                              void* d_out, int out_size, void* d_ws, size_t ws_size,
                              hipStream_t stream) {
  const float* s_in  = (const float*)d_in[0];
  const float* V_in  = (const float*)d_in[1];
  const float* W_h   = (const float*)d_in[2];
  const float* W_V   = (const float*)d_in[3];
  const float* W_s_w = (const float*)d_in[4];
  const float* W_s_b = (const float*)d_in[5];
  const float* W_g_w = (const float*)d_in[6];
  const float* W_g_b = (const float*)d_in[7];
  float* out = (float*)d_out;
  float* s_out_g = out;
  float* V_out_g = out + (size_t)NNODES * 128;
  hipLaunchKernelGGL(prep_kernel, dim3(52), dim3(256), 0, stream,
                     W_h, W_V, W_s_w, W_g_w);
  hipLaunchKernelGGL(gvp_kernel, dim3(NNODES / (BN * TILES)), dim3(256), 0, stream,
                     s_in, V_in, W_s_b, W_g_b, s_out_g, V_out_g);
}

// Round 8
// 110.183 us; speedup vs baseline: 1.9613x; 1.9613x over previous
//
#include <hip/hip_runtime.h>
#include <hip/hip_bf16.h>
#include <math.h>

#define NNODES 131072
#define BN 32

typedef __attribute__((ext_vector_type(8))) short bf16x8;
typedef __attribute__((ext_vector_type(4))) float f32x4;

// bf16 weights (prep): W_h [128*64] @0 | W_s [128*256] @8192 | W_g [64*128] @40960
__device__ short g_w[49152];
// bf16 fused weight Wc[o][v] = sum_h W_V[o][h]*W_h[h][v], [64*64] row-major
__device__ short g_wc[4096];

__device__ __forceinline__ short f2b(float f) {
  union { float f; unsigned u; } x; x.f = f;
  unsigned r = x.u + 0x7fffu + ((x.u >> 16) & 1u);
  return (short)(r >> 16);
}
// hardware bf16 convert (1 VALU op; compiler may pack pairs to v_cvt_pk_bf16_f32)
__device__ __forceinline__ short c2b(float f) {
  __hip_bfloat16 h = __float2bfloat16(f);
  return *reinterpret_cast<short*>(&h);
}

__global__ void prep_kernel(const float* __restrict__ W_h, const float* __restrict__ W_V,
                            const float* __restrict__ W_s_w, const float* __restrict__ W_g_w) {
  int b = blockIdx.x;
  if (b < 48) {
    int i4 = (b * 256 + threadIdx.x) * 4;
    const float* src;
    if (i4 < 8192)       src = W_h   + i4;
    else if (i4 < 40960) src = W_s_w + (i4 - 8192);
    else                 src = W_g_w + (i4 - 40960);
    float4 q = *(const float4*)src;
    short4 p;
    p.x = f2b(q.x); p.y = f2b(q.y); p.z = f2b(q.z); p.w = f2b(q.w);
    *(short4*)(g_w + i4) = p;
  } else {
    // Wc = W_V @ W_h : 4096 entries, 4 blocks x 256 threads x 4 entries
    int gid = (b - 48) * 256 + threadIdx.x;   // 0..1023
    int o  = gid >> 4;
    int v0 = (gid & 15) * 4;
    float a0 = 0.f, a1 = 0.f, a2 = 0.f, a3 = 0.f;
    #pragma unroll 8
    for (int h = 0; h < 128; ++h) {
      float wv = W_V[o * 128 + h];
      float4 wh = *(const float4*)(W_h + h * 64 + v0);
      a0 += wv * wh.x; a1 += wv * wh.y; a2 += wv * wh.z; a3 += wv * wh.w;
    }
    short4 p;
    p.x = f2b(a0); p.y = f2b(a1); p.z = f2b(a2); p.w = f2b(a3);
    *(short4*)(g_wc + o * 64 + v0) = p;
  }
}

// LDS (36864 B -> 4 blocks/CU):
//   Vt   @0     (12288): [96][64]  bf16 s128 swz   rows c*32+nl
//   SC   @12288 (8192) : [32][128] bf16 s256 swz   staged s
//   NORM @20480 (8192) : [32][128] bf16 s256 swz
//   SOUT @28672 (8192) : [32][128] bf16 s256 swz
//   VST  @0     (24576): [32][192] f32  overlays Vt+SC+NORM-head
// Barriers: B1 (Vt/SC ready), B2 (NORM ready), B3 (SOUT ready), B4 (VST ready).
// Staging map: thread t -> nl=t>>3 (node), vg/kg=t&7: contiguous 96B/64B loads,
// shift-only addressing, b128 LDS writes, hardware cvt.

__global__ __launch_bounds__(256, 4)
void gvp_kernel(const float* __restrict__ s_in, const float* __restrict__ V_in,
                const float* __restrict__ W_s_b, const float* __restrict__ W_g_b,
                float* __restrict__ s_out_g, float* __restrict__ V_out_g)
{
  __shared__ __align__(16) char smem[36864];
  char*  const Vt   = smem;
  float* const VST  = (float*)smem;
  char*  const SC   = smem + 12288;
  char*  const NORM = smem + 20480;
  char*  const SOUT = smem + 28672;

  const short* const g_wh = g_w;
  const short* const g_ws = g_w + 8192;
  const short* const g_wg = g_w + 40960;

  const int t    = threadIdx.x;
  const int lane = t & 63;
  const int w    = t >> 6;
  const int l15  = lane & 15;
  const int lk8  = (lane >> 4) << 3;  // 0,8,16,24 : k-offset of A/B frag
  const int r4   = (lane >> 4) << 2;  // 0,4,8,12  : row-offset of C frag
  const long n0  = (long)blockIdx.x * BN;

  // ---- stage V tile: thread (nl, vg) loads 24 contiguous floats of node nl ----
  {
    const int nl = t >> 3;        // 0..31
    const int vg = t & 7;         // 0..7
    const int v0 = vg << 3;       // 0,8,..,56
    const float* vp = V_in + (n0 + nl) * 192 + v0 * 3;   // 96B contiguous
    float4 q0 = *(const float4*)(vp);
    float4 q1 = *(const float4*)(vp + 4);
    float4 q2 = *(const float4*)(vp + 8);
    float4 q3 = *(const float4*)(vp + 12);
    float4 q4 = *(const float4*)(vp + 16);
    float4 q5 = *(const float4*)(vp + 20);
    float fl[24];
    *(float4*)(fl)      = q0; *(float4*)(fl + 4)  = q1;
    *(float4*)(fl + 8)  = q2; *(float4*)(fl + 12) = q3;
    *(float4*)(fl + 16) = q4; *(float4*)(fl + 20) = q5;
    #pragma unroll
    for (int c = 0; c < 3; ++c) {
      int row = (c << 5) + nl;
      bf16x8 p;
      #pragma unroll
      for (int j = 0; j < 8; ++j) p[j] = c2b(fl[j * 3 + c]);
      unsigned a = (unsigned)(row * 128) + (((unsigned)(v0 * 2)) ^ (unsigned)((row & 7) << 4));
      *(bf16x8*)(Vt + a) = p;
    }
  }
  // ---- stage s tile: thread (nl, kg) loads 16 contiguous floats ----
  {
    const int nl = t >> 3;
    const int kg = t & 7;
    const int k0 = kg << 4;       // 0,16,..,112
    const float* sp = s_in + (n0 + nl) * 128 + k0;       // 64B contiguous
    float4 q0 = *(const float4*)(sp);
    float4 q1 = *(const float4*)(sp + 4);
    float4 q2 = *(const float4*)(sp + 8);
    float4 q3 = *(const float4*)(sp + 12);
    bf16x8 pa, pb;
    pa[0] = c2b(q0.x); pa[1] = c2b(q0.y); pa[2] = c2b(q0.z); pa[3] = c2b(q0.w);
    pa[4] = c2b(q1.x); pa[5] = c2b(q1.y); pa[6] = c2b(q1.z); pa[7] = c2b(q1.w);
    pb[0] = c2b(q2.x); pb[1] = c2b(q2.y); pb[2] = c2b(q2.z); pb[3] = c2b(q2.w);
    pb[4] = c2b(q3.x); pb[5] = c2b(q3.y); pb[6] = c2b(q3.z); pb[7] = c2b(q3.w);
    unsigned sw = (unsigned)((nl & 7) << 4);
    unsigned aA = (unsigned)(nl * 256) + (((unsigned)(k0 * 2)) ^ sw);
    unsigned aB = (unsigned)(nl * 256) + (((unsigned)(k0 * 2 + 16)) ^ sw);
    *(bf16x8*)(SC + aA) = pa;
    *(bf16x8*)(SC + aB) = pb;
  }
  __syncthreads();  // B1: Vt/SC visible

  // ---- GEMM1 (Vh) + GEMM2 (V_out_pre via fused Wc), shared Vt A-frags, K=64 ----
  f32x4 acc1[6][2];
  f32x4 acc2[6];
  #pragma unroll
  for (int rt = 0; rt < 6; ++rt) {
    f32x4 z = {0.f, 0.f, 0.f, 0.f};
    acc1[rt][0] = z; acc1[rt][1] = z; acc2[rt] = z;
  }
  {
    bf16x8 bf1[2][2];
    #pragma unroll
    for (int cc = 0; cc < 2; ++cc) {
      int h = ((2 * w + cc) << 4) + l15;
      #pragma unroll
      for (int ks = 0; ks < 2; ++ks)
        bf1[cc][ks] = *(const bf16x8*)(g_wh + h * 64 + (ks << 5) + lk8);
    }
    bf16x8 bc[2];
    {
      int o = (w << 4) + l15;
      bc[0] = *(const bf16x8*)(g_wc + o * 64 + lk8);
      bc[1] = *(const bf16x8*)(g_wc + o * 64 + 32 + lk8);
    }
    #pragma unroll
    for (int rt = 0; rt < 6; ++rt) {
      int row = (rt << 4) + l15;
      unsigned sw = (unsigned)((row & 7) << 4);
      bf16x8 af0 = *(const bf16x8*)(Vt + row * 128 + (((unsigned)(lk8 * 2)) ^ sw));
      bf16x8 af1 = *(const bf16x8*)(Vt + row * 128 + (((unsigned)((32 + lk8) * 2)) ^ sw));
      #pragma unroll
      for (int cc = 0; cc < 2; ++cc) {
        acc1[rt][cc] = __builtin_amdgcn_mfma_f32_16x16x32_bf16(af0, bf1[cc][0], acc1[rt][cc], 0, 0, 0);
        acc1[rt][cc] = __builtin_amdgcn_mfma_f32_16x16x32_bf16(af1, bf1[cc][1], acc1[rt][cc], 0, 0, 0);
      }
      acc2[rt] = __builtin_amdgcn_mfma_f32_16x16x32_bf16(af0, bc[0], acc2[rt], 0, 0, 0);
      acc2[rt] = __builtin_amdgcn_mfma_f32_16x16x32_bf16(af1, bc[1], acc2[rt], 0, 0, 0);
    }
  }

  // ---- Vh_norm -> NORM ----
  #pragma unroll
  for (int cc = 0; cc < 2; ++cc) {
    int col = ((2 * w + cc) << 4) + l15;
    #pragma unroll
    for (int rt = 0; rt < 2; ++rt) {
      #pragma unroll
      for (int i = 0; i < 4; ++i) {
        int nl = (rt << 4) + r4 + i;
        float x0 = acc1[rt][cc][i];
        float x1 = acc1[rt + 2][cc][i];
        float x2 = acc1[rt + 4][cc][i];
        float nrm = sqrtf(x0 * x0 + x1 * x1 + x2 * x2);
        unsigned a = (unsigned)(nl * 256) + (((unsigned)(col * 2)) ^ (unsigned)((nl & 7) << 4));
        *(short*)(NORM + a) = c2b(nrm);
      }
    }
  }
  __syncthreads();  // B2: NORM visible

  // ---- GEMM3: s_out = relu([s|norm]·W_s^T + b); 32x128, K=256 ----
  // wave w owns output cols [w*32, w*32+32): line-local stores
  f32x4 acc3[2][2];
  {
    f32x4 z = {0.f, 0.f, 0.f, 0.f};
    acc3[0][0] = z; acc3[0][1] = z; acc3[1][0] = z; acc3[1][1] = z;
  }
  #pragma unroll
  for (int ks = 0; ks < 8; ++ks) {
    bf16x8 b3[2];
    #pragma unroll
    for (int cc = 0; cc < 2; ++cc) {
      int o = (w << 5) + (cc << 4) + l15;
      b3[cc] = *(const bf16x8*)(g_ws + o * 256 + (ks << 5) + lk8);
    }
    #pragma unroll
    for (int rt = 0; rt < 2; ++rt) {
      int row = (rt << 4) + l15;
      unsigned sw = (unsigned)((row & 7) << 4);
      bf16x8 a;
      if (ks < 4) {
        a = *(const bf16x8*)(SC + row * 256 + (((unsigned)(((ks << 5) + lk8) * 2)) ^ sw));
      } else {
        a = *(const bf16x8*)(NORM + row * 256 + (((unsigned)((((ks - 4) << 5) + lk8) * 2)) ^ sw));
      }
      acc3[rt][0] = __builtin_amdgcn_mfma_f32_16x16x32_bf16(a, b3[0], acc3[rt][0], 0, 0, 0);
      acc3[rt][1] = __builtin_amdgcn_mfma_f32_16x16x32_bf16(a, b3[1], acc3[rt][1], 0, 0, 0);
    }
  }

  // ---- s_out epilogue: line-local global stores + SOUT stage ----
  {
    float bias0 = W_s_b[(w << 5) + l15];
    float bias1 = W_s_b[(w << 5) + 16 + l15];
    #pragma unroll
    for (int rt = 0; rt < 2; ++rt) {
      #pragma unroll
      for (int i = 0; i < 4; ++i) {
        int row = (rt << 4) + r4 + i;
        unsigned sw = (unsigned)((row & 7) << 4);
        float v0 = fmaxf(acc3[rt][0][i] + bias0, 0.0f);
        float v1 = fmaxf(acc3[rt][1][i] + bias1, 0.0f);
        int col0 = (w << 5) + l15;
        s_out_g[(n0 + row) * 128 + col0]      = v0;
        s_out_g[(n0 + row) * 128 + col0 + 16] = v1;
        unsigned a0 = (unsigned)(row * 256) + (((unsigned)(col0 * 2)) ^ sw);
        unsigned a1 = (unsigned)(row * 256) + (((unsigned)((col0 + 16) * 2)) ^ sw);
        *(short*)(SOUT + a0) = c2b(v0);
        *(short*)(SOUT + a1) = c2b(v1);
      }
    }
  }
  __syncthreads();  // B3: SOUT ready; SC/NORM/Vt reads all done

  // ---- GEMM4: gate = sigmoid(s_out·W_g^T + b); C-frag lane-aligned with acc2 ----
  f32x4 acc4[2];
  { f32x4 z = {0.f, 0.f, 0.f, 0.f}; acc4[0] = z; acc4[1] = z; }
  {
    int o = (w << 4) + l15;
    #pragma unroll
    for (int ks = 0; ks < 4; ++ks) {
      bf16x8 b4 = *(const bf16x8*)(g_wg + o * 128 + (ks << 5) + lk8);
      #pragma unroll
      for (int rt = 0; rt < 2; ++rt) {
        int row = (rt << 4) + l15;
        bf16x8 a = *(const bf16x8*)(SOUT + row * 256 +
                     (((unsigned)(((ks << 5) + lk8) * 2)) ^ ((unsigned)((row & 7) << 4))));
        acc4[rt] = __builtin_amdgcn_mfma_f32_16x16x32_bf16(a, b4, acc4[rt], 0, 0, 0);
      }
    }
  }

  // ---- gate apply (in-lane) -> VST [32][192] f32 (overlays Vt+SC+NORM-head) ----
  {
    int col = (w << 4) + l15;
    float biasg = W_g_b[col];
    #pragma unroll
    for (int nlg = 0; nlg < 2; ++nlg) {
      #pragma unroll
      for (int i = 0; i < 4; ++i) {
        int nl = (nlg << 4) + r4 + i;
        float x = acc4[nlg][i] + biasg;
        float sg = 1.0f / (1.0f + __expf(-x));
        VST[nl * 192 + col * 3 + 0] = acc2[nlg][i]     * sg;
        VST[nl * 192 + col * 3 + 1] = acc2[2 + nlg][i] * sg;
        VST[nl * 192 + col * 3 + 2] = acc2[4 + nlg][i] * sg;
      }
    }
  }
  __syncthreads();  // B4: VST visible

  // ---- coalesced full-line V_out store (float4 x 64 lanes = 1KB/instr) ----
  {
    float4* Vo = (float4*)(V_out_g + n0 * 192);
    const float4* Vs = (const float4*)VST;
    #pragma unroll
    for (int i = 0; i < 6; ++i) {
      int idx = t + 256 * i;
      Vo[idx] = Vs[idx];
    }
  }
}

extern "C" void kernel_launch(void* const* d_in, const int* in_sizes, int n_in,
                              void* d_out, int out_size, void* d_ws, size_t ws_size,
                              hipStream_t stream) {
  const float* s_in  = (const float*)d_in[0];
  const float* V_in  = (const float*)d_in[1];
  const float* W_h   = (const float*)d_in[2];
  const float* W_V   = (const float*)d_in[3];
  const float* W_s_w = (const float*)d_in[4];
  const float* W_s_b = (const float*)d_in[5];
  const float* W_g_w = (const float*)d_in[6];
  const float* W_g_b = (const float*)d_in[7];
  float* out = (float*)d_out;
  float* s_out_g = out;
  float* V_out_g = out + (size_t)NNODES * 128;
  hipLaunchKernelGGL(prep_kernel, dim3(52), dim3(256), 0, stream,
                     W_h, W_V, W_s_w, W_g_w);
  hipLaunchKernelGGL(gvp_kernel, dim3(NNODES / BN), dim3(256), 0, stream,
                     s_in, V_in, W_s_b, W_g_b, s_out_g, V_out_g);
}